// Round 14
// baseline (162.797 us; speedup 1.0000x reference)
//
#include <hip/hip_runtime.h>

namespace {

constexpr int kN = 100;   // subactors
constexpr int kH = 16;    // hidden
constexpr int kS = 6;     // state
constexpr int kB = 128;   // batch
constexpr int kT = 128;   // time
constexpr int kNS = kN * kS;   // 600 floats per (b,t) row
constexpr int kXB = kT * kNS;  // 76800 floats per b
constexpr float kL2E = 1.44269504088896340736f;  // log2(e)

typedef float f32x4 __attribute__((ext_vector_type(4)));
typedef float vf2 __attribute__((ext_vector_type(2)));
typedef unsigned u32x2 __attribute__((ext_vector_type(2)));
typedef short bf16x8 __attribute__((ext_vector_type(8)));

union Frag {
  unsigned u[4];
  bf16x8 v;
};

// Manual RNE pack (proven; r10 showed v_cvt_pk_bf16_f32 breaks numerics).
__device__ __forceinline__ unsigned pkbf(float a, float b) {
  unsigned ua = __builtin_bit_cast(unsigned, a);
  unsigned ub = __builtin_bit_cast(unsigned, b);
  ua += 0x7fffu + ((ua >> 16) & 1u);
  ub += 0x7fffu + ((ub >> 16) & 1u);
  return (ua >> 16) | (ub & 0xffff0000u);
}

__device__ __forceinline__ float rcp_fast(float v) {
  return __builtin_amdgcn_rcpf(v);
}
__device__ __forceinline__ float exp2_fast(float v) {
  return __builtin_amdgcn_exp2f(v);
}
__device__ __forceinline__ vf2 pkfma(vf2 a, vf2 b, vf2 c) {
  return __builtin_elementwise_fma(a, b, c);
}

__device__ __forceinline__ f32x4 mfma16(bf16x8 a, bf16x8 b, f32x4 c) {
  return __builtin_amdgcn_mfma_f32_16x16x32_bf16(a, b, c, 0, 0, 0);
}

// K-slot permutation for lane-local B:
//   quad q supplies k-slots [8q..8q+3] = h rows 4q..4q+3,
//   [8q+4,8q+5] = x comps 2q,2q+1 (q<3), rest 0.
__device__ __forceinline__ void mkA(Frag& F, int qt, const float* hrow,
                                    const float* xrow, float sc) {
  F.u[0] = F.u[1] = F.u[2] = F.u[3] = 0u;
  if (hrow) {
    F.u[0] = pkbf(hrow[4 * qt + 0] * sc, hrow[4 * qt + 1] * sc);
    F.u[1] = pkbf(hrow[4 * qt + 2] * sc, hrow[4 * qt + 3] * sc);
  }
  if (xrow && qt < 3) {
    F.u[2] = pkbf(xrow[2 * qt + 0] * sc, xrow[2 * qt + 1] * sc);
  }
}

}  // namespace

// Block = 2 waves, 800 blocks. Wave 0 = recurrence only (the serial chain,
// minus everything removable). Wave 1 = MLP head, fed h via an LDS ring
// (16 slots x 64 lanes x 8B): producer's packed P0,P1 are exactly the
// consumer's B fragment, lane-for-lane. One __syncthreads per 8-step window;
// window's x loads are issued at window start so the barrier's vmcnt drain
// hits retired loads.
__global__ __launch_bounds__(128) void actor_pc(
    const float* __restrict__ x, const float* __restrict__ Wih,
    const float* __restrict__ Whh, const float* __restrict__ bih,
    const float* __restrict__ bhh, const float* __restrict__ W1,
    const float* __restrict__ b1, const float* __restrict__ W2,
    const float* __restrict__ b2, const float* __restrict__ W3,
    const float* __restrict__ b3, float* __restrict__ out) {
  __shared__ unsigned shh[16 * 128];  // 16 slots x 64 lanes x 2 dwords = 8 KB

  const int tid = (int)threadIdx.x;
  const int wid = tid >> 6;   // 0 = producer, 1 = consumer
  const int lane = tid & 63;
  const int j = lane & 15;
  const int qt = lane >> 4;
  const int n = (int)blockIdx.x >> 3;
  const int bt = (int)blockIdx.x & 7;
  const int b = bt * 16 + j;

  // ---- producer constants (recurrence) ----
  Frag Ar, Az, Anh, Anx;
  f32x4 Cbr, Cbz, Cbhn, Cbin;
  const float* px =
      x + (size_t)b * kXB + (size_t)n * kS + (qt < 3 ? 2 * qt : 0);

  // ---- consumer constants (MLP) ----
  Frag Ay1, Ay2;
  f32x4 Cb1, Cb2;
  vf2 w301, w323;
  float b3s;
  float* outp = out + ((size_t)n * kB + b) * kT;

  if (wid == 0) {
    mkA(Ar, qt, Whh + ((size_t)n * 48 + j) * 16,
        Wih + ((size_t)n * 48 + j) * 6, kL2E);
    mkA(Az, qt, Whh + ((size_t)n * 48 + 16 + j) * 16,
        Wih + ((size_t)n * 48 + 16 + j) * 6, kL2E);
    mkA(Anh, qt, Whh + ((size_t)n * 48 + 32 + j) * 16, nullptr, 2.0f * kL2E);
    mkA(Anx, qt, nullptr, Wih + ((size_t)n * 48 + 32 + j) * 6, 2.0f * kL2E);
#pragma unroll
    for (int r = 0; r < 4; ++r) {
      const int gi = n * 48 + 4 * qt + r;
      Cbr[r] = (bih[gi] + bhh[gi]) * kL2E;
      Cbz[r] = (bih[gi + 16] + bhh[gi + 16]) * kL2E;
      Cbin[r] = bih[gi + 32] * 2.0f * kL2E;
      Cbhn[r] = bhh[gi + 32] * 2.0f * kL2E;
    }
  } else {
    mkA(Ay1, qt, W1 + ((size_t)n * 16 + j) * 16, nullptr, 1.0f);
    mkA(Ay2, qt, W2 + ((size_t)n * 16 + j) * 16, nullptr, 1.0f);
#pragma unroll
    for (int r = 0; r < 4; ++r) {
      const int hi = n * 16 + 4 * qt + r;
      Cb1[r] = b1[hi];
      Cb2[r] = b2[hi];
    }
    w301 = (vf2){W3[n * 16 + 4 * qt + 0], W3[n * 16 + 4 * qt + 1]};
    w323 = (vf2){W3[n * 16 + 4 * qt + 2], W3[n * 16 + 4 * qt + 3]};
    b3s = b3[n];
  }

  // producer state
  float2 xbuf[2][8];
  if (wid == 0) {
#pragma unroll
    for (int i = 0; i < 8; ++i)
      xbuf[0][i] = *(const float2*)(px + (size_t)i * kNS);
  }
  vf2 hp01 = (vf2){0.f, 0.f}, hp23 = (vf2){0.f, 0.f};
  unsigned P0 = 0u, P1 = 0u;

  const vf2 one2 = (vf2){1.f, 1.f};
  const vf2 m2 = (vf2){-2.f, -2.f};
  const vf2 z2 = (vf2){0.f, 0.f};

  for (int w = 0; w <= 16; ++w) {
    if (wid == 0) {
      if (w < 16) {
        // issue next-window x loads now (retire before this window's barrier)
        const int nb = (w + 1) & 1;
#pragma unroll
        for (int i = 0; i < 8; ++i) {
          int tc = 8 * (w + 1) + i;
          if (tc > kT - 1) tc = kT - 1;
          xbuf[nb][i] = *(const float2*)(px + (size_t)tc * kNS);
        }
        const int cb = w & 1;
#pragma unroll
        for (int k = 0; k < 8; ++k) {
          const int t = 8 * w + k;
          Frag Bf;
          Bf.u[0] = P0;
          Bf.u[1] = P1;
          Bf.u[2] = pkbf(xbuf[cb][k].x, xbuf[cb][k].y);
          Bf.u[3] = 0u;

          const f32x4 Cr = mfma16(Ar.v, Bf.v, Cbr);
          const f32x4 Cz = mfma16(Az.v, Bf.v, Cbz);
          const f32x4 Chn = mfma16(Anh.v, Bf.v, Cbhn);
          const f32x4 Cxn = mfma16(Anx.v, Bf.v, Cbin);

          vf2 cr01 = {Cr[0], Cr[1]}, cr23 = {Cr[2], Cr[3]};
          vf2 cz01 = {Cz[0], Cz[1]}, cz23 = {Cz[2], Cz[3]};
          vf2 chn01 = {Chn[0], Chn[1]}, chn23 = {Chn[2], Chn[3]};
          vf2 cxn01 = {Cxn[0], Cxn[1]}, cxn23 = {Cxn[2], Cxn[3]};

          vf2 er01 = {exp2_fast(-cr01.x), exp2_fast(-cr01.y)};
          vf2 er23 = {exp2_fast(-cr23.x), exp2_fast(-cr23.y)};
          vf2 dr01 = er01 + one2, dr23 = er23 + one2;
          vf2 rr01 = {rcp_fast(dr01.x), rcp_fast(dr01.y)};
          vf2 rr23 = {rcp_fast(dr23.x), rcp_fast(dr23.y)};

          vf2 ez01 = {exp2_fast(-cz01.x), exp2_fast(-cz01.y)};
          vf2 ez23 = {exp2_fast(-cz23.x), exp2_fast(-cz23.y)};
          vf2 dz01 = ez01 + one2, dz23 = ez23 + one2;
          vf2 zz01 = {rcp_fast(dz01.x), rcp_fast(dz01.y)};
          vf2 zz23 = {rcp_fast(dz23.x), rcp_fast(dz23.y)};

          vf2 np01 = pkfma(rr01, chn01, cxn01);
          vf2 np23 = pkfma(rr23, chn23, cxn23);
          vf2 en01 = {exp2_fast(np01.x), exp2_fast(np01.y)};
          vf2 en23 = {exp2_fast(np23.x), exp2_fast(np23.y)};
          vf2 dn01 = en01 + one2, dn23 = en23 + one2;
          vf2 rn01 = {rcp_fast(dn01.x), rcp_fast(dn01.y)};
          vf2 rn23 = {rcp_fast(dn23.x), rcp_fast(dn23.y)};
          vf2 nn01 = pkfma(m2, rn01, one2);
          vf2 nn23 = pkfma(m2, rn23, one2);

          hp01 = pkfma(zz01, hp01 - nn01, nn01);
          hp23 = pkfma(zz23, hp23 - nn23, nn23);
          P0 = pkbf(hp01.x, hp01.y);
          P1 = pkbf(hp23.x, hp23.y);

          // publish h_t (fire-and-forget; barrier orders visibility)
          *(u32x2*)&shh[(t & 15) * 128 + lane * 2] = (u32x2){P0, P1};
        }
      }
    } else {
      if (w >= 1) {
        const int t0 = 8 * (w - 1);
        float s4[4];
#pragma unroll
        for (int k = 0; k < 8; ++k) {
          const int t = t0 + k;
          const u32x2 P = *(const u32x2*)&shh[(t & 15) * 128 + lane * 2];
          Frag Bh;
          Bh.u[0] = P.x;
          Bh.u[1] = P.y;
          Bh.u[2] = 0u;
          Bh.u[3] = 0u;
          const f32x4 Cy1 = mfma16(Ay1.v, Bh.v, Cb1);
          vf2 a = __builtin_elementwise_max((vf2){Cy1[0], Cy1[1]}, z2);
          vf2 c = __builtin_elementwise_max((vf2){Cy1[2], Cy1[3]}, z2);
          Frag By;
          By.u[0] = pkbf(a.x, a.y);
          By.u[1] = pkbf(c.x, c.y);
          By.u[2] = 0u;
          By.u[3] = 0u;
          const f32x4 Cy2 = mfma16(Ay2.v, By.v, Cb2);
          vf2 a2 = __builtin_elementwise_max((vf2){Cy2[0], Cy2[1]}, z2);
          vf2 c2 = __builtin_elementwise_max((vf2){Cy2[2], Cy2[3]}, z2);
          vf2 p = pkfma(c2, w323, a2 * w301);
          s4[k & 3] = p.x + p.y;
          if ((k & 3) == 3) {
            float v0 = s4[0], v1 = s4[1], v2 = s4[2], v3 = s4[3];
            v0 += __shfl_xor(v0, 16);
            v1 += __shfl_xor(v1, 16);
            v2 += __shfl_xor(v2, 16);
            v3 += __shfl_xor(v3, 16);
            v0 += __shfl_xor(v0, 32);
            v1 += __shfl_xor(v1, 32);
            v2 += __shfl_xor(v2, 32);
            v3 += __shfl_xor(v3, 32);
            if (qt == 0) {
              float4 o = {fmaxf(v0 + b3s, 0.f), fmaxf(v1 + b3s, 0.f),
                          fmaxf(v2 + b3s, 0.f), fmaxf(v3 + b3s, 0.f)};
              *(float4*)(outp + (t - 3)) = o;
            }
          }
        }
      }
    }
    if (w < 16) __syncthreads();
  }
}

extern "C" void kernel_launch(void* const* d_in, const int* in_sizes, int n_in,
                              void* d_out, int out_size, void* d_ws,
                              size_t ws_size, hipStream_t stream) {
  const float* x = (const float*)d_in[0];
  const float* Wih = (const float*)d_in[1];
  const float* Whh = (const float*)d_in[2];
  const float* bih = (const float*)d_in[3];
  const float* bhh = (const float*)d_in[4];
  const float* W1 = (const float*)d_in[5];
  const float* b1 = (const float*)d_in[6];
  const float* W2 = (const float*)d_in[7];
  const float* b2 = (const float*)d_in[8];
  const float* W3 = (const float*)d_in[9];
  const float* b3 = (const float*)d_in[10];
  float* out = (float*)d_out;

  actor_pc<<<dim3(kN * 8), dim3(128), 0, stream>>>(x, Wih, Whh, bih, bhh, W1,
                                                   b1, W2, b2, W3, b3, out);
}